// Round 2
// baseline (69851.886 us; speedup 1.0000x reference)
//
#include <hip/hip_runtime.h>

typedef _Float16 f16;
typedef __attribute__((ext_vector_type(8))) _Float16 f16x8;
typedef __attribute__((ext_vector_type(4))) float f32x4;

#define LL   256
#define BB   512
#define DD   512
#define NN3  1536
#define NWG  256

// ---- workspace byte offsets ----
#define OFF_BAR    ((size_t)0)
#define OFF_HBASE  ((size_t)1024)
#define OFF_HSF    (OFF_HBASE + (size_t)BB*DD*4)
#define OFF_ACC    (OFF_HSF  + (size_t)BB*DD*4)
#define OFF_HS16   (OFF_ACC  + (size_t)BB*DD*4)
#define OFF_XE16   (OFF_HS16 + (size_t)BB*DD*2)
#define OFF_WP     (OFF_XE16 + (size_t)NWG*32*DD*2)
#define OFF_WXP    (OFF_WP   + (size_t)64*NN3*8*2)
#define OFF_LY1P   (OFF_WXP  + (size_t)64*NN3*8*2)
#define OFF_WINP   (OFF_LY1P + (size_t)64*DD*8*2)
#define OFF_BF     (OFF_WINP + (size_t)4*DD*8*2)

__device__ __forceinline__ float sigmoid_f(float x) {
  return __builtin_amdgcn_rcpf(1.f + __expf(-x));
}
__device__ __forceinline__ float tanh_f(float x) {
  float ax = fabsf(x);
  float e  = __expf(-2.f * ax);
  float t  = (1.f - e) * __builtin_amdgcn_rcpf(1.f + e);
  return copysignf(t, x);
}

// Pack weights into fp16 fragment-order layouts.
// Fused gate/lin matrix columns interleaved per 48: [z i0..i0+15 | r ... | lin ...]
__global__ void pack_kernel(const float* __restrict__ Win, const float* __restrict__ Wx,
                            const float* __restrict__ Wg,  const float* __restrict__ bg,
                            const float* __restrict__ Wlin,const float* __restrict__ blin,
                            const float* __restrict__ Ly1, char* __restrict__ ws)
{
  f16* WP   = (f16*)(ws + OFF_WP);
  f16* WXP  = (f16*)(ws + OFF_WXP);
  f16* LY1P = (f16*)(ws + OFF_LY1P);
  f16* WINP = (f16*)(ws + OFF_WINP);
  float* BF = (float*)(ws + OFF_BF);
  const int stride = gridDim.x * blockDim.x;
  const int idx0 = blockIdx.x * blockDim.x + threadIdx.x;

  for (int e = idx0; e < 64*NN3*8; e += stride) {
    int kb = e / (NN3*8); int rem = e - kb*(NN3*8); int n = rem >> 3; int h = rem & 7;
    int k = kb*8 + h;
    int ib = n/48, wi = n - ib*48; int s = wi >> 4, il = wi & 15;
    int i = ib*16 + il;
    float wv, xv;
    if (s == 0)      { wv = Wg[(size_t)i*DD + k];         xv = Wx[(size_t)i*DD + k]; }
    else if (s == 1) { wv = Wg[(size_t)(512+i)*DD + k];   xv = Wx[(size_t)(512+i)*DD + k]; }
    else             { wv = Wlin[(size_t)i*DD + k];       xv = Wx[(size_t)(1024+i)*DD + k]; }
    WP[e] = (f16)wv; WXP[e] = (f16)xv;
  }
  for (int e = idx0; e < 64*DD*8; e += stride) {
    int kb = e / (DD*8); int rem = e - kb*(DD*8); int n = rem >> 3; int h = rem & 7;
    LY1P[e] = (f16)Ly1[(size_t)n*DD + kb*8 + h];
  }
  for (int e = idx0; e < 4*DD*8; e += stride) {
    int kb = e / (DD*8); int rem = e - kb*(DD*8); int n = rem >> 3; int h = rem & 7;
    int c = kb*8 + h;
    WINP[e] = (c < 15) ? (f16)Win[n*15 + c] : (f16)0.f;
  }
  for (int n = idx0; n < NN3; n += stride) {
    int ib = n/48, wi = n - ib*48; int s = wi >> 4, il = wi & 15;
    int i = ib*16 + il;
    BF[n] = (s == 0) ? bg[i] : (s == 1) ? bg[512+i] : blin[i];
  }
}

__launch_bounds__(256, 1)
__global__ void scan_kernel(const float* __restrict__ seq, const float* __restrict__ state0,
                            const float* __restrict__ bin, const float* __restrict__ Ly2,
                            float* __restrict__ out, char* __restrict__ ws)
{
  float* hbase = (float*)(ws + OFF_HBASE);
  float* hsf   = (float*)(ws + OFF_HSF);
  float* accb  = (float*)(ws + OFF_ACC);
  f16*   hs16  = (f16*)(ws + OFF_HS16);
  f16*   xe16  = (f16*)(ws + OFF_XE16);
  const f16* WP   = (const f16*)(ws + OFF_WP);
  const f16* WXP  = (const f16*)(ws + OFF_WXP);
  const f16* LY1P = (const f16*)(ws + OFF_LY1P);
  const f16* WINP = (const f16*)(ws + OFF_WINP);
  const float* BF = (const float*)(ws + OFF_BF);
  int* bcnt = (int*)(ws + OFF_BAR);
  int* bgen = bcnt + 1;

  const int wg = blockIdx.x;
  const int mg = wg >> 4, ng = wg & 15;
  const int m0 = mg << 5;        // 32 batch rows per WG
  const int n0 = ng * 96;        // 96 packed cols per WG
  const int tid = threadIdx.x;
  const int w  = tid >> 6, l = tid & 63;
  const int mw = (w & 1) << 4;   // wave row offset
  const int nw = (w >> 1) * 48;  // wave col offset (one z/r/lin triple-block)
  const int lr = l & 15, lk = l >> 4;

  __shared__ __align__(16) f16 bsh[2*768*8];   // B tile double buffer (24 KB)
  __shared__ __align__(16) f16 a1sh[32*32];    // seq tile (2 KB)
  __shared__ float lxsh[32*96];                // lx tile, persists across F phases (12 KB)

  f16* myxe = xe16 + (size_t)wg * 32 * DD;

  auto gbar = [&]() {
    __syncthreads();
    if (tid == 0) {
      __threadfence();
      int g = __hip_atomic_load(bgen, __ATOMIC_RELAXED, __HIP_MEMORY_SCOPE_AGENT);
      int a = __hip_atomic_fetch_add(bcnt, 1, __ATOMIC_ACQ_REL, __HIP_MEMORY_SCOPE_AGENT);
      if (a == NWG - 1) {
        __hip_atomic_store(bcnt, 0, __ATOMIC_RELAXED, __HIP_MEMORY_SCOPE_AGENT);
        __hip_atomic_store(bgen, g + 1, __ATOMIC_RELEASE, __HIP_MEMORY_SCOPE_AGENT);
      } else {
        while (__hip_atomic_load(bgen, __ATOMIC_ACQUIRE, __HIP_MEMORY_SCOPE_AGENT) == g)
          __builtin_amdgcn_s_sleep(2);
      }
      __threadfence();
    }
    __syncthreads();
  };

  // 16x48-per-wave GEMM over K=512: A (global fp16, row stride DD) x packed B -> 3 acc frags
  auto gemm48 = [&](const f16* __restrict__ Ag, const f16* __restrict__ Bg, f32x4* av) {
    f32x4 z4 = {0.f,0.f,0.f,0.f};
    av[0] = z4; av[1] = z4; av[2] = z4;
    const int g0 = tid, g1 = tid + 256, g2 = tid + 512;
    const int kb0 = g0/96, nn0 = g0 - kb0*96;
    const int kb1 = g1/96, nn1 = g1 - kb1*96;
    const int kb2 = g2/96, nn2 = g2 - kb2*96;
    const f16* bp0 = Bg + ((size_t)kb0*NN3 + n0 + nn0)*8;
    const f16* bp1 = Bg + ((size_t)kb1*NN3 + n0 + nn1)*8;
    const f16* bp2 = Bg + ((size_t)kb2*NN3 + n0 + nn2)*8;
    const f16* arow = Ag + (size_t)(mw + lr)*DD + lk*8;
    float4 s0 = *(const float4*)bp0;
    float4 s1 = *(const float4*)bp1;
    float4 s2 = *(const float4*)bp2;
    for (int sl = 0; sl < 8; ++sl) {
      f16* bb = bsh + (sl & 1)*(768*8);
      *(float4*)(bb + g0*8) = s0;
      *(float4*)(bb + g1*8) = s1;
      *(float4*)(bb + g2*8) = s2;
      if (sl < 7) {
        size_t so = (size_t)(sl+1)*(8*(size_t)NN3*8);
        s0 = *(const float4*)(bp0 + so);
        s1 = *(const float4*)(bp1 + so);
        s2 = *(const float4*)(bp2 + so);
      }
      __syncthreads();
      #pragma unroll
      for (int kk = 0; kk < 2; ++kk) {
        f16x8 a = *(const f16x8*)(arow + sl*64 + kk*32);
        const f16* bl = bb + ((kk*4 + lk)*96 + nw)*8;
        f16x8 b0v = *(const f16x8*)(bl + lr*8);
        f16x8 b1v = *(const f16x8*)(bl + (16 + lr)*8);
        f16x8 b2v = *(const f16x8*)(bl + (32 + lr)*8);
        av[0] = __builtin_amdgcn_mfma_f32_16x16x32_f16(a, b0v, av[0], 0, 0, 0);
        av[1] = __builtin_amdgcn_mfma_f32_16x16x32_f16(a, b1v, av[1], 0, 0, 0);
        av[2] = __builtin_amdgcn_mfma_f32_16x16x32_f16(a, b2v, av[2], 0, 0, 0);
      }
    }
  };

  // ---- init state from state0 ----
  for (int e = tid; e < 32*DD; e += 256) {
    int r = e >> 9, d = e & 511;
    float v = state0[d];
    size_t gi = (size_t)(m0 + r)*DD + d;
    hbase[gi] = v; hsf[gi] = v; hs16[gi] = (f16)v;
  }
  gbar();

  #pragma unroll 1
  for (int t = 0; t < LL; ++t) {
    // ================= LX + Y phase =================
    {
      // seq tile -> a1sh (fp16, 16B-granule XOR swizzle), cols 16..31 zeroed
      {
        int tt = tid & 127;
        int r = tt >> 2, cq = tt & 3;
        if (tid < 128) {
          const float* sp = seq + (((size_t)t*BB + m0 + r) << 4) + cq*4;
          float4 v = *(const float4*)sp;
          int gq = cq >> 1, hf = cq & 1;
          f16* p = (f16*)((char*)a1sh + r*64 + ((gq ^ (r & 3))*16) + hf*8);
          p[0]=(f16)v.x; p[1]=(f16)v.y; p[2]=(f16)v.z; p[3]=(f16)v.w;
        } else {
          int gq = 2 + (cq >> 1), hf = cq & 1;
          f16* p = (f16*)((char*)a1sh + r*64 + ((gq ^ (r & 3))*16) + hf*8);
          p[0]=(f16)0.f; p[1]=(f16)0.f; p[2]=(f16)0.f; p[3]=(f16)0.f;
        }
      }
      __syncthreads();
      // xe = tanh(seq_x @ Win^T + bin) via K=32 MFMA; wave w -> cols [w*128, w*128+128)
      #pragma unroll
      for (int rf = 0; rf < 2; ++rf) {
        int ar = rf*16 + lr;
        f16x8 a1 = *(const f16x8*)((char*)a1sh + ar*64 + ((lk ^ (ar & 3))*16));
        #pragma unroll
        for (int cf = 0; cf < 8; ++cf) {
          int col = (w << 7) + (cf << 4) + lr;
          f16x8 b1 = *(const f16x8*)(WINP + ((size_t)lk*DD + col)*8);
          f32x4 d = {0.f,0.f,0.f,0.f};
          d = __builtin_amdgcn_mfma_f32_16x16x32_f16(a1, b1, d, 0, 0, 0);
          float bv = bin[col];
          #pragma unroll
          for (int r2 = 0; r2 < 4; ++r2) {
            float v = tanh_f(d[r2] + bv);
            myxe[(size_t)(rf*16 + (lk << 2) + r2)*DD + col] = (f16)v;
          }
        }
      }
      __threadfence();
      __syncthreads();
      // lx tile = xe @ WXP -> LDS (persists through the 4 F phases)
      f32x4 alx[3];
      gemm48(myxe, WXP, alx);
      #pragma unroll
      for (int f = 0; f < 3; ++f)
        #pragma unroll
        for (int r2 = 0; r2 < 4; ++r2)
          lxsh[(mw + (lk<<2) + r2)*96 + nw + (f<<4) + lr] = alx[f][r2];
      // ---- Y: out row t = tanh(h @ Ly1^T) @ Ly2^T from current hs16 ----
      {
        const int c0 = (ng << 5) + ((w >> 1) << 4);
        f32x4 ty = {0.f,0.f,0.f,0.f};
        const f16* ya = hs16 + (size_t)(m0 + mw + lr)*DD + lk*8;
        const f16* yb = LY1P + ((size_t)lk*DD + c0 + lr)*8;
        #pragma unroll
        for (int ks = 0; ks < 16; ++ks) {
          f16x8 a = *(const f16x8*)(ya + ks*32);
          f16x8 b = *(const f16x8*)(yb + (size_t)ks*4*DD*8);
          ty = __builtin_amdgcn_mfma_f32_16x16x32_f16(a, b, ty, 0, 0, 0);
        }
        const int cc = c0 + lr;
        float l2[8];
        #pragma unroll
        for (int o = 0; o < 8; ++o) l2[o] = Ly2[o*DD + cc];
        float part[4][8];
        #pragma unroll
        for (int r2 = 0; r2 < 4; ++r2) {
          float tv = tanh_f(ty[r2]);
          #pragma unroll
          for (int o = 0; o < 8; ++o) part[r2][o] = tv * l2[o];
        }
        #pragma unroll
        for (int ms = 1; ms < 16; ms <<= 1)
          #pragma unroll
          for (int r2 = 0; r2 < 4; ++r2)
            #pragma unroll
            for (int o = 0; o < 8; ++o)
              part[r2][o] += __shfl_xor(part[r2][o], ms, 64);
        if (lr == 0) {
          float* orow = out + (size_t)t*BB*8;
          #pragma unroll
          for (int r2 = 0; r2 < 4; ++r2) {
            int b = m0 + mw + (lk << 2) + r2;
            #pragma unroll
            for (int o = 0; o < 8; ++o)
              atomicAdd(orow + b*8 + o, part[r2][o]);
          }
        }
      }
    }
    gbar();
    // ================= 4 RK4 f-eval phases =================
    if (t < LL-1) {
      #pragma unroll 1
      for (int j = 0; j < 4; ++j) {
        f32x4 av[3];
        gemm48(hs16 + (size_t)m0*DD, WP, av);
        const int iw = (ng << 5) + ((w >> 1) << 4) + lr;   // state index
        const float bfz = BF[n0 + nw + lr];
        const float bfr = BF[n0 + nw + 16 + lr];
        const float bfl = BF[n0 + nw + 32 + lr];
        #pragma unroll
        for (int r2 = 0; r2 < 4; ++r2) {
          const int rloc = mw + (lk << 2) + r2;
          const int b = m0 + rloc;
          const float* lxr = lxsh + rloc*96 + nw;
          float dtb = (t == 0) ? 0.f : seq[(((size_t)(t-1)*BB + b) << 4) + 15];
          float z   = sigmoid_f(av[0][r2] + lxr[lr]      + bfz);
          float rg  = sigmoid_f(av[1][r2] + lxr[16 + lr] + bfr);
          float lin = tanh_f(lxr[32 + lr] + rg * av[2][r2] + bfl);
          size_t gi = (size_t)b*DD + iw;
          float hcur = hsf[gi];
          float kk = z * (lin - hcur);       // MEANDT == 1
          float hb = hbase[gi];
          float hn;
          if (j == 0)      { accb[gi] = kk;        hn = hb + 0.5f*dtb*kk; }
          else if (j == 1) { accb[gi] += 2.f*kk;   hn = hb + 0.5f*dtb*kk; }
          else if (j == 2) { accb[gi] += 2.f*kk;   hn = hb + dtb*kk; }
          else             { hn = hb + dtb*(accb[gi] + kk)*(1.f/6.f); hbase[gi] = hn; }
          hsf[gi] = hn; hs16[gi] = (f16)hn;
        }
        gbar();
      }
    }
  }
}

extern "C" void kernel_launch(void* const* d_in, const int* in_sizes, int n_in,
                              void* d_out, int out_size, void* d_ws, size_t ws_size,
                              hipStream_t stream)
{
  const float* seq    = (const float*)d_in[0];
  const float* state0 = (const float*)d_in[1];
  const float* Win    = (const float*)d_in[2];
  const float* bin_   = (const float*)d_in[3];
  const float* Wx     = (const float*)d_in[4];
  const float* Wg     = (const float*)d_in[5];
  const float* bg     = (const float*)d_in[6];
  const float* Wlin   = (const float*)d_in[7];
  const float* blin   = (const float*)d_in[8];
  const float* Ly1    = (const float*)d_in[9];
  const float* Ly2    = (const float*)d_in[10];
  char* ws = (char*)d_ws;

  hipMemsetAsync(d_out, 0, (size_t)out_size * sizeof(float), stream);  // y accumulated via atomics
  hipMemsetAsync(d_ws, 0, 1024, stream);                               // barrier counter/gen

  pack_kernel<<<dim3(512), dim3(256), 0, stream>>>(Win, Wx, Wg, bg, Wlin, blin, Ly1, ws);
  scan_kernel<<<dim3(NWG), dim3(256), 0, stream>>>(seq, state0, bin_, Ly2, (float*)d_out, ws);
}

// Round 4
// 20195.889 us; speedup vs baseline: 3.4587x; 3.4587x over previous
//
#include <hip/hip_runtime.h>

typedef _Float16 f16;
typedef __attribute__((ext_vector_type(8))) _Float16 f16x8;
typedef __attribute__((ext_vector_type(4))) float f32x4;

#define LL   256
#define BB   512
#define DD   512
#define NN3  1536
#define NWG  256
// LDS: [0,96K) WPl resident | [96K,108K) bschar (WXP stream / a1sh) | [108K,140K) xesh
#define SMEM_BYTES (98304 + 12288 + 32768)

// ---- workspace byte offsets ----
#define OFF_BAR    ((size_t)0)
#define OFF_HSA    ((size_t)8192)
#define OFF_HSB    (OFF_HSA  + (size_t)BB*DD*2)
#define OFF_HB16   (OFF_HSB  + (size_t)BB*DD*2)
#define OFF_WP     (OFF_HB16 + (size_t)BB*DD*2)
#define OFF_WXP    (OFF_WP   + (size_t)64*NN3*8*2)
#define OFF_LY1P   (OFF_WXP  + (size_t)64*NN3*8*2)
#define OFF_WINP   (OFF_LY1P + (size_t)64*DD*8*2)
#define OFF_BF     (OFF_WINP + (size_t)4*DD*8*2)

__device__ __forceinline__ float sigmoid_f(float x) {
  return __builtin_amdgcn_rcpf(1.f + __expf(-x));
}
__device__ __forceinline__ float tanh_f(float x) {
  float ax = fabsf(x);
  float e  = __expf(-2.f * ax);
  float t  = (1.f - e) * __builtin_amdgcn_rcpf(1.f + e);
  return copysignf(t, x);
}

// Pack weights into fp16 fragment-order layouts.
// Fused gate/lin matrix columns interleaved per 48: [z i0..i0+15 | r ... | lin ...]
__global__ void pack_kernel(const float* __restrict__ Win, const float* __restrict__ Wx,
                            const float* __restrict__ Wg,  const float* __restrict__ bg,
                            const float* __restrict__ Wlin,const float* __restrict__ blin,
                            const float* __restrict__ Ly1, char* __restrict__ ws)
{
  f16* WP   = (f16*)(ws + OFF_WP);
  f16* WXP  = (f16*)(ws + OFF_WXP);
  f16* LY1P = (f16*)(ws + OFF_LY1P);
  f16* WINP = (f16*)(ws + OFF_WINP);
  float* BF = (float*)(ws + OFF_BF);
  const int stride = gridDim.x * blockDim.x;
  const int idx0 = blockIdx.x * blockDim.x + threadIdx.x;

  for (int e = idx0; e < 64*NN3*8; e += stride) {
    int kb = e / (NN3*8); int rem = e - kb*(NN3*8); int n = rem >> 3; int h = rem & 7;
    int k = kb*8 + h;
    int ib = n/48, wi = n - ib*48; int s = wi >> 4, il = wi & 15;
    int i = ib*16 + il;
    float wv, xv;
    if (s == 0)      { wv = Wg[(size_t)i*DD + k];         xv = Wx[(size_t)i*DD + k]; }
    else if (s == 1) { wv = Wg[(size_t)(512+i)*DD + k];   xv = Wx[(size_t)(512+i)*DD + k]; }
    else             { wv = Wlin[(size_t)i*DD + k];       xv = Wx[(size_t)(1024+i)*DD + k]; }
    WP[e] = (f16)wv; WXP[e] = (f16)xv;
  }
  for (int e = idx0; e < 64*DD*8; e += stride) {
    int kb = e / (DD*8); int rem = e - kb*(DD*8); int n = rem >> 3; int h = rem & 7;
    LY1P[e] = (f16)Ly1[(size_t)n*DD + kb*8 + h];
  }
  for (int e = idx0; e < 4*DD*8; e += stride) {
    int kb = e / (DD*8); int rem = e - kb*(DD*8); int n = rem >> 3; int h = rem & 7;
    int c = kb*8 + h;
    WINP[e] = (c < 15) ? (f16)Win[n*15 + c] : (f16)0.f;
  }
  for (int n = idx0; n < NN3; n += stride) {
    int ib = n/48, wi = n - ib*48; int s = wi >> 4, il = wi & 15;
    int i = ib*16 + il;
    BF[n] = (s == 0) ? bg[i] : (s == 1) ? bg[512+i] : blin[i];
  }
}

__launch_bounds__(256, 1)
__global__ void scan_kernel(const float* __restrict__ seq, const float* __restrict__ state0,
                            const float* __restrict__ bin, const float* __restrict__ Ly2,
                            float* __restrict__ out, char* __restrict__ ws)
{
  f16*   hsA   = (f16*)(ws + OFF_HSA);    // stage buffers (fp16 A-operand), ping-pong
  f16*   hsB   = (f16*)(ws + OFF_HSB);
  f16*   hb16  = (f16*)(ws + OFF_HB16);   // step-base h (fp16 A-operand, j0 + Y)
  const f16* WP   = (const f16*)(ws + OFF_WP);
  const f16* WXP  = (const f16*)(ws + OFF_WXP);
  const f16* LY1P = (const f16*)(ws + OFF_LY1P);
  const f16* WINP = (const f16*)(ws + OFF_WINP);
  const float* BF = (const float*)(ws + OFF_BF);

  extern __shared__ __align__(16) char smem[];
  char* bschar = smem + 98304;     // 12 KB stream buffer (WXP slices / seq tile)
  char* xechar = smem + 110592;    // 32 KB xe tile (row-major [32][512] f16, XOR-swizzled)

  const int wg = blockIdx.x;
  const int mg = wg & 15, ng = wg >> 4;    // group = same mg (16 WGs, XCD-colocated under %8 dispatch)
  const int m0 = mg << 5;                  // 32 batch rows
  const int n0 = ng * 96;                  // 96 packed cols
  const int tid = threadIdx.x;
  const int w  = tid >> 6, l = tid & 63;
  const int mw = (w & 1) << 4;
  const int nw = (w >> 1) * 48;
  const int lr = l & 15, lk = l >> 4;

  int* bline = (int*)(ws + OFF_BAR) + mg*64;   // per-group barrier line, 256B apart

  auto gbar = [&]() {
    __syncthreads();
    if (tid == 0) {
      int g = __hip_atomic_load(bline+1, __ATOMIC_RELAXED, __HIP_MEMORY_SCOPE_AGENT);
      int a = __hip_atomic_fetch_add(bline, 1, __ATOMIC_ACQ_REL, __HIP_MEMORY_SCOPE_AGENT);
      if (a == 15) {
        __hip_atomic_store(bline, 0, __ATOMIC_RELAXED, __HIP_MEMORY_SCOPE_AGENT);
        __hip_atomic_store(bline+1, g+1, __ATOMIC_RELEASE, __HIP_MEMORY_SCOPE_AGENT);
      } else {
        while (__hip_atomic_load(bline+1, __ATOMIC_RELAXED, __HIP_MEMORY_SCOPE_AGENT) == g)
          __builtin_amdgcn_s_sleep(2);
        __builtin_amdgcn_fence(__ATOMIC_ACQUIRE, "agent");   // one inv at exit, not per poll
      }
    }
    __syncthreads();
  };

  // ---- stage resident WP slice into LDS (once), XOR-swizzled 16B granules ----
  for (int g = tid; g < 6144; g += 256) {
    int kb = g / 96, nl = g - kb*96;
    int dst = (kb*1536 + nl*16) ^ ((kb & 7) << 4);
    *(float4*)(smem + dst) = *(const float4*)(WP + ((size_t)kb*NN3 + n0 + nl)*8);
  }
  // ---- init hb16 (this WG's 32 rows x 32 state cols) ----
  for (int e = tid; e < 1024; e += 256) {
    int r = e >> 5, c = e & 31;
    hb16[(size_t)(m0+r)*DD + (ng<<5) + c] = (f16)state0[(ng<<5)+c];
  }
  const int iw = (ng<<5) + ((w>>1)<<4) + lr;
  float hbase[4], hstage[4], acc[4];
  {
    float sv = state0[iw];
    #pragma unroll
    for (int r2 = 0; r2 < 4; ++r2) { hbase[r2] = sv; hstage[r2] = sv; acc[r2] = 0.f; }
  }
  const float bfz = BF[n0+nw+lr], bfr = BF[n0+nw+16+lr], bfl = BF[n0+nw+32+lr];
  const int c0 = (ng<<5) + ((w>>1)<<4);
  float l2[8];
  #pragma unroll
  for (int o = 0; o < 8; ++o) l2[o] = Ly2[o*DD + c0 + lr];
  const size_t gibase = (size_t)(m0 + mw + (lk<<2))*DD + iw;
  gbar();   // hb16 visible group-wide

  f32x4 alx0, alx1, alx2;

  #pragma unroll 1
  for (int t = 0; t < LL; ++t) {
    const bool last = (t == LL-1);
    float dtb[4];
    if (!last) {
      // --- seq tile -> bschar (fp16, 16B-granule XOR swizzle), cols 16..31 zeroed ---
      {
        int tt = tid & 127;
        int r = tt >> 2, cq = tt & 3;
        int gq = (tid < 128 ? 0 : 2) + (cq >> 1), hf = cq & 1;
        f16* p = (f16*)(bschar + r*64 + ((gq ^ (r & 3))*16) + hf*8);
        if (tid < 128) {
          float4 v = *(const float4*)(seq + (((size_t)t*BB + m0 + r) << 4) + cq*4);
          p[0]=(f16)v.x; p[1]=(f16)v.y; p[2]=(f16)v.z; p[3]=(f16)v.w;
        } else { p[0]=(f16)0.f; p[1]=(f16)0.f; p[2]=(f16)0.f; p[3]=(f16)0.f; }
      }
      #pragma unroll
      for (int r2 = 0; r2 < 4; ++r2)
        dtb[r2] = (t == 0) ? 0.f
                 : seq[(((size_t)(t-1)*BB + m0 + mw + (lk<<2) + r2) << 4) + 15];
      __syncthreads();
      // --- xe = tanh(seq_x @ Win^T + bin), K=32 MFMA -> xesh (LDS, XOR-swizzled rows) ---
      #pragma unroll
      for (int rf = 0; rf < 2; ++rf) {
        int ar = rf*16 + lr;
        f16x8 a1 = *(const f16x8*)(bschar + ar*64 + ((lk ^ (ar & 3))*16));
        #pragma unroll
        for (int cf = 0; cf < 8; ++cf) {
          int col = (w << 7) + (cf << 4) + lr;
          f16x8 b1 = *(const f16x8*)(WINP + ((size_t)lk*DD + col)*8);
          f32x4 d = {0.f,0.f,0.f,0.f};
          d = __builtin_amdgcn_mfma_f32_16x16x32_f16(a1, b1, d, 0, 0, 0);
          float bv = bin[col];
          #pragma unroll
          for (int r2 = 0; r2 < 4; ++r2) {
            int row = rf*16 + (lk << 2) + r2;
            *(f16*)(xechar + row*1024 + ((col*2) ^ ((row & 7) << 4))) = (f16)tanh_f(d[r2] + bv);
          }
        }
      }
      __syncthreads();   // bschar reads done (reusable); xesh visible
      // --- LX: alx = xe @ WXP ; A from xesh, B streamed WXP->bschar (single buffer) ---
      {
        f16x8 axf[16];
        {
          const int row = mw + lr;
          #pragma unroll
          for (int ks = 0; ks < 16; ++ks)
            axf[ks] = *(const f16x8*)(xechar + row*1024 + ((lk*16 + ks*64) ^ ((row & 7) << 4)));
        }
        const int kb0 = tid/96,        nn0p = tid - kb0*96;
        const int kb1 = (tid+256)/96,  nn1p = (tid+256) - kb1*96;
        const int kb2 = (tid+512)/96,  nn2p = (tid+512) - kb2*96;
        const int d0 = (kb0*1536 + nn0p*16) ^ (kb0 << 4);
        const int d1 = (kb1*1536 + nn1p*16) ^ (kb1 << 4);
        const int d2 = (kb2*1536 + nn2p*16) ^ (kb2 << 4);
        float4 s0 = *(const float4*)(WXP + ((size_t)kb0*NN3 + n0 + nn0p)*8);
        float4 s1 = *(const float4*)(WXP + ((size_t)kb1*NN3 + n0 + nn1p)*8);
        float4 s2 = *(const float4*)(WXP + ((size_t)kb2*NN3 + n0 + nn2p)*8);
        f32x4 L0 = {0.f,0.f,0.f,0.f}, L1 = L0, L2 = L0;
        #pragma unroll 1
        for (int sl = 0; sl < 8; ++sl) {
          if (sl) __syncthreads();
          *(float4*)(bschar + d0) = s0;
          *(float4*)(bschar + d1) = s1;
          *(float4*)(bschar + d2) = s2;
          if (sl < 7) {
            size_t so = (size_t)(sl+1)*8*NN3*8;
            s0 = *(const float4*)(WXP + ((size_t)kb0*NN3 + n0 + nn0p)*8 + so);
            s1 = *(const float4*)(WXP + ((size_t)kb1*NN3 + n0 + nn1p)*8 + so);
            s2 = *(const float4*)(WXP + ((size_t)kb2*NN3 + n0 + nn2p)*8 + so);
          }
          __syncthreads();
          #pragma unroll
          for (int kk = 0; kk < 2; ++kk) {
            int kbl = kk*4 + lk;
            f16x8 b0 = *(const f16x8*)(bschar + ((kbl*1536 + (nw+lr)*16)    ^ (kbl<<4)));
            f16x8 b1 = *(const f16x8*)(bschar + ((kbl*1536 + (nw+16+lr)*16) ^ (kbl<<4)));
            f16x8 b2 = *(const f16x8*)(bschar + ((kbl*1536 + (nw+32+lr)*16) ^ (kbl<<4)));
            f16x8 a = axf[sl*2 + kk];
            L0 = __builtin_amdgcn_mfma_f32_16x16x32_f16(a, b0, L0, 0, 0, 0);
            L1 = __builtin_amdgcn_mfma_f32_16x16x32_f16(a, b1, L1, 0, 0, 0);
            L2 = __builtin_amdgcn_mfma_f32_16x16x32_f16(a, b2, L2, 0, 0, 0);
          }
        }
        alx0 = L0; alx1 = L1; alx2 = L2;
      }
    }
    // --- A-fragments from hb16 (h at step start) ---
    f16x8 af[16];
    {
      const f16* arow = hb16 + (size_t)(m0 + mw + lr)*DD + lk*8;
      #pragma unroll
      for (int ks = 0; ks < 16; ++ks) af[ks] = *(const f16x8*)(arow + ks*32);
    }
    // --- fused j0 GEMM (B resident in LDS) + Y GEMM ---
    f32x4 av0 = {0.f,0.f,0.f,0.f}, av1 = av0, av2 = av0, ty = av0;
    #pragma unroll
    for (int ks = 0; ks < 16; ++ks) {
      int kb = (ks<<2) + lk;
      int x  = (kb & 7) << 4;
      f16x8 b0 = *(const f16x8*)(smem + ((kb*1536 + (nw+lr)*16)    ^ x));
      f16x8 b1 = *(const f16x8*)(smem + ((kb*1536 + (nw+16+lr)*16) ^ x));
      f16x8 b2 = *(const f16x8*)(smem + ((kb*1536 + (nw+32+lr)*16) ^ x));
      f16x8 yb = *(const f16x8*)(LY1P + ((size_t)kb*DD + c0 + lr)*8);
      av0 = __builtin_amdgcn_mfma_f32_16x16x32_f16(af[ks], b0, av0, 0, 0, 0);
      av1 = __builtin_amdgcn_mfma_f32_16x16x32_f16(af[ks], b1, av1, 0, 0, 0);
      av2 = __builtin_amdgcn_mfma_f32_16x16x32_f16(af[ks], b2, av2, 0, 0, 0);
      ty  = __builtin_amdgcn_mfma_f32_16x16x32_f16(af[ks], yb, ty, 0, 0, 0);
    }
    // --- Y finish: tanh, Ly2 multiply, 16-lane reduce, atomics ---
    {
      float part[4][8];
      #pragma unroll
      for (int r2 = 0; r2 < 4; ++r2) {
        float tv = tanh_f(ty[r2]);
        #pragma unroll
        for (int o = 0; o < 8; ++o) part[r2][o] = tv * l2[o];
      }
      #pragma unroll
      for (int ms = 1; ms < 16; ms <<= 1)
        #pragma unroll
        for (int r2 = 0; r2 < 4; ++r2)
          #pragma unroll
          for (int o = 0; o < 8; ++o)
            part[r2][o] += __shfl_xor(part[r2][o], ms, 64);
      if (lr == 0) {
        float* orow = out + (size_t)t*BB*8;
        #pragma unroll
        for (int r2 = 0; r2 < 4; ++r2) {
          int b = m0 + mw + (lk << 2) + r2;
          #pragma unroll
          for (int o = 0; o < 8; ++o)
            atomicAdd(orow + b*8 + o, part[r2][o]);
        }
      }
    }
    if (last) break;
    // --- j0 epilogue (state in registers); stage -> hsA ---
    #pragma unroll
    for (int r2 = 0; r2 < 4; ++r2) {
      float z   = sigmoid_f(av0[r2] + alx0[r2] + bfz);
      float rg  = sigmoid_f(av1[r2] + alx1[r2] + bfr);
      float lin = tanh_f(alx2[r2] + rg*av2[r2] + bfl);
      float kk  = z * (lin - hstage[r2]);
      acc[r2] = kk;
      float hn = hbase[r2] + 0.5f*dtb[r2]*kk;
      hstage[r2] = hn;
      hsA[gibase + (size_t)r2*DD] = (f16)hn;
    }
    gbar();
    // --- j1..j3 (stage ping-pong: j1 hsA->hsB, j2 hsB->hsA, j3 hsA->hb16) ---
    #pragma unroll
    for (int j = 1; j < 4; ++j) {
      const f16* rbuf = (j == 2) ? hsB : hsA;
      f16x8 afj[16];
      {
        const f16* arow = rbuf + (size_t)(m0 + mw + lr)*DD + lk*8;
        #pragma unroll
        for (int ks = 0; ks < 16; ++ks) afj[ks] = *(const f16x8*)(arow + ks*32);
      }
      f32x4 zz = {0.f,0.f,0.f,0.f};
      f32x4 j0a = zz, j1a = zz, j2a = zz;
      #pragma unroll
      for (int ks = 0; ks < 16; ++ks) {
        int kb = (ks<<2) + lk;
        int x  = (kb & 7) << 4;
        f16x8 b0 = *(const f16x8*)(smem + ((kb*1536 + (nw+lr)*16)    ^ x));
        f16x8 b1 = *(const f16x8*)(smem + ((kb*1536 + (nw+16+lr)*16) ^ x));
        f16x8 b2 = *(const f16x8*)(smem + ((kb*1536 + (nw+32+lr)*16) ^ x));
        j0a = __builtin_amdgcn_mfma_f32_16x16x32_f16(afj[ks], b0, j0a, 0, 0, 0);
        j1a = __builtin_amdgcn_mfma_f32_16x16x32_f16(afj[ks], b1, j1a, 0, 0, 0);
        j2a = __builtin_amdgcn_mfma_f32_16x16x32_f16(afj[ks], b2, j2a, 0, 0, 0);
      }
      #pragma unroll
      for (int r2 = 0; r2 < 4; ++r2) {
        float z   = sigmoid_f(j0a[r2] + alx0[r2] + bfz);
        float rg  = sigmoid_f(j1a[r2] + alx1[r2] + bfr);
        float lin = tanh_f(alx2[r2] + rg*j2a[r2] + bfl);
        float kk  = z * (lin - hstage[r2]);
        float hn;
        if (j == 1)      { acc[r2] += 2.f*kk; hn = hbase[r2] + 0.5f*dtb[r2]*kk; }
        else if (j == 2) { acc[r2] += 2.f*kk; hn = hbase[r2] + dtb[r2]*kk; }
        else             { hn = hbase[r2] + dtb[r2]*(acc[r2] + kk)*(1.f/6.f); hbase[r2] = hn; }
        hstage[r2] = hn;
        if (j == 1)      hsB[gibase + (size_t)r2*DD] = (f16)hn;
        else if (j == 2) hsA[gibase + (size_t)r2*DD] = (f16)hn;
        else             hb16[gibase + (size_t)r2*DD] = (f16)hn;
      }
      gbar();
    }
  }
}

extern "C" void kernel_launch(void* const* d_in, const int* in_sizes, int n_in,
                              void* d_out, int out_size, void* d_ws, size_t ws_size,
                              hipStream_t stream)
{
  const float* seq    = (const float*)d_in[0];
  const float* state0 = (const float*)d_in[1];
  const float* Win    = (const float*)d_in[2];
  const float* bin_   = (const float*)d_in[3];
  const float* Wx     = (const float*)d_in[4];
  const float* Wg     = (const float*)d_in[5];
  const float* bg     = (const float*)d_in[6];
  const float* Wlin   = (const float*)d_in[7];
  const float* blin   = (const float*)d_in[8];
  const float* Ly1    = (const float*)d_in[9];
  const float* Ly2    = (const float*)d_in[10];
  char* ws = (char*)d_ws;

  hipFuncSetAttribute((const void*)scan_kernel,
                      hipFuncAttributeMaxDynamicSharedMemorySize, SMEM_BYTES);

  hipMemsetAsync(d_out, 0, (size_t)out_size * sizeof(float), stream);  // y accumulated via atomics
  hipMemsetAsync(d_ws, 0, 8192, stream);                               // barrier lines

  pack_kernel<<<dim3(512), dim3(256), 0, stream>>>(Win, Wx, Wg, bg, Wlin, blin, Ly1, ws);
  scan_kernel<<<dim3(NWG), dim3(256), SMEM_BYTES, stream>>>(seq, state0, bin_, Ly2, (float*)d_out, ws);
}